// Round 1
// 638.557 us; speedup vs baseline: 1.1047x; 1.1047x over previous
//
#include <hip/hip_runtime.h>

#define SEQ   512
#define BATCH 256
#define INDIM 784
#define HID   10
#define NC4   196   // INDIM / 4
#define CHUNK 56    // columns staged per iteration (784 = 14 * 56)
#define NCH   14
#define STR   257   // LDS row stride in floats (odd -> <=2-way bank aliasing)
#define PF    8     // scan prefetch depth (steps); 40 loads in flight < vmcnt cap 63

typedef float f4 __attribute__((ext_vector_type(4)));

// ---------------------------------------------------------------------------
// Kernel 1: xi[row][j] = x[row] . W_ih[j] + b_ih[j] + b_hh[j],  row = t*B+b
// Lane-per-row: block of 256 threads owns 256 rows. x is staged through LDS
// TRANSPOSED (lds[c][r]) in CHUNK-column slabs so the compute-phase read
// lds[c*STR + tid] is conflict-free (stride-1 across lanes) and the write
// (4c+k)*STR + r with odd STR is <=2-way (free). W is read with wave-uniform
// indices -> scalar loads on the SMEM pipe, leaving LDS/VALU clean.
// Next chunk is prefetched into registers to overlap global latency.
// x loads are nontemporal: 411 MB streamed exactly once, no reuse.
// ---------------------------------------------------------------------------
__global__ __launch_bounds__(256) void xproj_kernel(
    const float* __restrict__ x, const float* __restrict__ Wih,
    const float* __restrict__ bih, const float* __restrict__ bhh,
    float* __restrict__ xi)
{
    __shared__ float lds[CHUNK * STR];   // 57,568 B -> 2 blocks/CU

    const int tid  = threadIdx.x;
    const long row0 = (long)blockIdx.x * 256;
    const f4* x4 = (const f4*)x + row0 * NC4;

    float acc[HID];
#pragma unroll
    for (int j = 0; j < HID; ++j) acc[j] = bih[j] + bhh[j];

    f4 stg[14];
    // preload chunk 0: 256 rows x 14 float4, coalesced (c4 fastest)
#pragma unroll
    for (int k = 0; k < 14; ++k) {
        const int idx = k * 256 + tid;
        const int c4 = idx % 14, r = idx / 14;
        stg[k] = __builtin_nontemporal_load(&x4[(long)r * NC4 + c4]);
    }

    for (int ch = 0; ch < NCH; ++ch) {
        // staged regs -> LDS, transposed
#pragma unroll
        for (int k = 0; k < 14; ++k) {
            const int idx = k * 256 + tid;
            const int c4 = idx % 14, r = idx / 14;
            const int cb = c4 * 4;
            lds[(cb + 0) * STR + r] = stg[k][0];
            lds[(cb + 1) * STR + r] = stg[k][1];
            lds[(cb + 2) * STR + r] = stg[k][2];
            lds[(cb + 3) * STR + r] = stg[k][3];
        }
        __syncthreads();

        // prefetch next chunk while computing this one
        if (ch + 1 < NCH) {
#pragma unroll
            for (int k = 0; k < 14; ++k) {
                const int idx = k * 256 + tid;
                const int c4 = idx % 14, r = idx / 14;
                stg[k] = __builtin_nontemporal_load(
                    &x4[(long)r * NC4 + (ch + 1) * 14 + c4]);
            }
        }

        const float* wch = Wih + ch * CHUNK;
#pragma unroll 4
        for (int c = 0; c < CHUNK; ++c) {
            const float xv = lds[c * STR + tid];
#pragma unroll
            for (int j = 0; j < HID; ++j)
                acc[j] = fmaf(xv, wch[j * INDIM + c], acc[j]);
        }
        __syncthreads();
    }

    float* po = xi + (row0 + tid) * HID;
#pragma unroll
    for (int j = 0; j < HID; ++j) po[j] = acc[j];
}

// ---------------------------------------------------------------------------
// Kernel 2: h_t = relu(xi_t + h_{t-1} @ W_hh^T). 2 threads per batch element
// (xor-1 pair in-wave), each owns 5 hidden dims; W columns permuted per
// thread so no runtime register indexing. Dot split into two 5-deep fma
// chains (+1 add) to shorten the per-step critical path. 8 blocks x 64
// threads: one wave per CU.
//
// NEW: 8-deep register ring prefetch of xi. The old 1-step-ahead prefetch
// exposed ~400-900 cy of L3/remote-L2 latency every step (xi was written by
// 256 CUs across all 8 XCDs; the 8 scan blocks mostly miss their local L2).
// Ring buf[PF][5] with fully static indexing (t-loop unrolled by PF) gives
// an 8-step (~880 cy) issue-to-use window; 40 loads in flight. Loads are
// issued at the TOP of each step (buf[i] is copied to cur first) so the
// window is the full 8 steps. Tail 8 steps peeled -> no guard branch in the
// main loop.
// ---------------------------------------------------------------------------
__global__ __launch_bounds__(64) void scan_kernel(
    const float* __restrict__ xi, const float* __restrict__ Whh,
    float* __restrict__ out)
{
    const int gid  = blockIdx.x * 64 + threadIdx.x;    // 0..511
    const int b    = gid >> 1;
    const int half = gid & 1;
    const int j0   = half * 5;

    // W[jj][k]: row j0+jj, columns permuted: k<5 -> dim k+j0, k>=5 -> k-j0
    float W[5][10];
#pragma unroll
    for (int jj = 0; jj < 5; ++jj)
#pragma unroll
        for (int k = 0; k < 10; ++k) {
            const int col = (k < 5) ? (k + j0) : (k - j0);
            W[jj][k] = Whh[(j0 + jj) * HID + col];
        }

    float h[10];
#pragma unroll
    for (int k = 0; k < 10; ++k) h[k] = 0.f;

    const float* xib  = xi  + b * HID + j0;
    float*       outb = out + b * HID + j0;

    // fill the ring: steps 0..PF-1
    float buf[PF][5];
#pragma unroll
    for (int i = 0; i < PF; ++i) {
        const float* p = xib + (long)i * (BATCH * HID);
#pragma unroll
        for (int jj = 0; jj < 5; ++jj) buf[i][jj] = p[jj];
    }

    for (int t0 = 0; t0 < SEQ - PF; t0 += PF) {
#pragma unroll
        for (int i = 0; i < PF; ++i) {
            const int t = t0 + i;

            float cur[5];
#pragma unroll
            for (int jj = 0; jj < 5; ++jj) cur[jj] = buf[i][jj];

            // issue prefetch for t+PF immediately (full 8-step window)
            const float* p = xib + (long)(t + PF) * (BATCH * HID);
#pragma unroll
            for (int jj = 0; jj < 5; ++jj) buf[i][jj] = p[jj];

            float s[5];
#pragma unroll
            for (int jj = 0; jj < 5; ++jj) {
                float a0 = cur[jj];
                float a1 = W[jj][5] * h[5];
#pragma unroll
                for (int k = 0; k < 5; ++k) a0 = fmaf(W[jj][k], h[k], a0);
#pragma unroll
                for (int k = 6; k < 10; ++k) a1 = fmaf(W[jj][k], h[k], a1);
                s[jj] = fmaxf(a0 + a1, 0.f);
            }

            float* po = outb + (long)t * (BATCH * HID);
#pragma unroll
            for (int jj = 0; jj < 5; ++jj) po[jj] = s[jj];

#pragma unroll
            for (int jj = 0; jj < 5; ++jj) {
                h[jj]     = s[jj];
                h[5 + jj] = __shfl_xor(s[jj], 1, 64);
            }
        }
    }

    // tail: last PF steps, ring already holds them, no prefetch
#pragma unroll
    for (int i = 0; i < PF; ++i) {
        const int t = SEQ - PF + i;

        float s[5];
#pragma unroll
        for (int jj = 0; jj < 5; ++jj) {
            float a0 = buf[i][jj];
            float a1 = W[jj][5] * h[5];
#pragma unroll
            for (int k = 0; k < 5; ++k) a0 = fmaf(W[jj][k], h[k], a0);
#pragma unroll
            for (int k = 6; k < 10; ++k) a1 = fmaf(W[jj][k], h[k], a1);
            s[jj] = fmaxf(a0 + a1, 0.f);
        }

        float* po = outb + (long)t * (BATCH * HID);
#pragma unroll
        for (int jj = 0; jj < 5; ++jj) po[jj] = s[jj];

#pragma unroll
        for (int jj = 0; jj < 5; ++jj) {
            h[jj]     = s[jj];
            h[5 + jj] = __shfl_xor(s[jj], 1, 64);
        }
    }

    float* pl = out + (long)SEQ * BATCH * HID + b * HID + j0;
#pragma unroll
    for (int jj = 0; jj < 5; ++jj) pl[jj] = h[jj];
}

// ---------------------------------------------------------------------------
extern "C" void kernel_launch(void* const* d_in, const int* in_sizes, int n_in,
                              void* d_out, int out_size, void* d_ws, size_t ws_size,
                              hipStream_t stream)
{
    const float* x   = (const float*)d_in[0];
    const float* Wih = (const float*)d_in[1];
    const float* Whh = (const float*)d_in[2];
    const float* bih = (const float*)d_in[3];
    const float* bhh = (const float*)d_in[4];
    float* out = (float*)d_out;
    float* xi  = (float*)d_ws;   // SEQ*BATCH*HID floats = 5.24 MB

    xproj_kernel<<<512, 256, 0, stream>>>(x, Wih, bih, bhh, xi);
    scan_kernel<<<8, 64, 0, stream>>>(xi, Whh, out);
}